// Round 1
// baseline (1181.917 us; speedup 1.0000x reference)
//
#include <hip/hip_runtime.h>
#include <hip/hip_bf16.h>
#include <math.h>

// ---------------- types / constants ----------------
#define AS1 __attribute__((address_space(1)))
#define AS3 __attribute__((address_space(3)))

typedef __bf16 bf16;
typedef __bf16 bf16x2 __attribute__((ext_vector_type(2)));
typedef __bf16 bf16x4 __attribute__((ext_vector_type(4)));
typedef __bf16 bf16x8 __attribute__((ext_vector_type(8)));
typedef float  f32x4  __attribute__((ext_vector_type(4)));

#define DIM   1024
#define MLPH  2048
#define HEADS 16
#define HD    64
#define WIN   128
#define NBAT  4
#define SEQ   8192
#define MTOK  (NBAT*SEQ)   // 32768 tokens

// async global->LDS, 16B per lane, dest must be wave-uniform base (+lane*16 by HW)
__device__ __forceinline__ void gload_lds16(const void* g, void* l) {
  __builtin_amdgcn_global_load_lds((const AS1 void*)g, (AS3 void*)l, 16, 0, 0);
}

// ---------------- fp32 -> bf16 weight convert ----------------
__global__ __launch_bounds__(256) void cvt_w(const float* __restrict__ in,
                                             bf16* __restrict__ out, int n4) {
  int i = blockIdx.x * 256 + threadIdx.x;
  if (i < n4) {
    float4 v = ((const float4*)in)[i];
    bf16x4 o;
    o[0] = (bf16)v.x; o[1] = (bf16)v.y; o[2] = (bf16)v.z; o[3] = (bf16)v.w;
    ((bf16x4*)out)[i] = o;
  }
}

// ---------------- LayerNorm (one row of 1024 per block) -> bf16 ----------------
__global__ __launch_bounds__(256) void ln_bf16(const float* __restrict__ x,
                                               const float* __restrict__ w,
                                               const float* __restrict__ b,
                                               bf16* __restrict__ out) {
  int row = blockIdx.x;
  int t = threadIdx.x;
  float4 v = ((const float4*)(x + (size_t)row * DIM))[t];
  float s  = v.x + v.y + v.z + v.w;
  float ss = v.x*v.x + v.y*v.y + v.z*v.z + v.w*v.w;
#pragma unroll
  for (int off = 32; off; off >>= 1) { s += __shfl_xor(s, off); ss += __shfl_xor(ss, off); }
  __shared__ float sb[8];
  int wid = t >> 6, lane = t & 63;
  if (!lane) { sb[wid] = s; sb[wid + 4] = ss; }
  __syncthreads();
  s  = sb[0] + sb[1] + sb[2] + sb[3];
  ss = sb[4] + sb[5] + sb[6] + sb[7];
  float mu = s * (1.0f / DIM);
  float rs = rsqrtf(ss * (1.0f / DIM) - mu * mu + 1e-5f);
  float4 wv = ((const float4*)w)[t];
  float4 bv = ((const float4*)b)[t];
  bf16x4 o;
  o[0] = (bf16)((v.x - mu) * rs * wv.x + bv.x);
  o[1] = (bf16)((v.y - mu) * rs * wv.y + bv.y);
  o[2] = (bf16)((v.z - mu) * rs * wv.z + bv.z);
  o[3] = (bf16)((v.w - mu) * rs * wv.w + bv.w);
  ((bf16x4*)(out + (size_t)row * DIM))[t] = o;
}

// ---------------- BT-GEMM: C[M,N] = A[M,K] * Bw[N,K]^T (+epilogue) ----------------
// EPI 0: +bias -> bf16 ; EPI 1: +bias +resid -> fp32 ; EPI 2: gelu(+bias) -> bf16
template<int N, int K, int EPI>
__global__ __launch_bounds__(256) void gemm_bt(const bf16* __restrict__ A,
                                               const bf16* __restrict__ Bw,
                                               const float* __restrict__ bias,
                                               const float* __restrict__ resid,
                                               void* __restrict__ Cout) {
  __shared__ alignas(16) bf16 As[128 * 64];  // [row][64] rowbytes=128, XOR-swizzled
  __shared__ alignas(16) bf16 Bs[128 * 64];
  const int tid = threadIdx.x;
  const int wid = tid >> 6;
  const int lane = tid & 63;
  const int wm = wid >> 1, wn = wid & 1;   // 2x2 wave grid, 64x64 out per wave
  const int m0 = blockIdx.y * 128;
  const int n0 = blockIdx.x * 128;

  f32x4 acc[4][4] = {};

  const char* Ab = (const char*)A;
  const char* Bb = (const char*)Bw;
  const int o_base = (wid << 12) + lane * 16;

  for (int k0 = 0; k0 < K; k0 += 64) {
#pragma unroll
    for (int r = 0; r < 4; ++r) {
      int o = o_base + (r << 10);
      int row = o >> 7;
      int cb = (o & 127) ^ ((row & 7) << 4);   // pre-swizzled source (T2, both-sides)
      gload_lds16(Ab + ((size_t)(m0 + row) * K + k0) * 2 + cb,
                  (char*)As + (wid << 12) + (r << 10));
      gload_lds16(Bb + ((size_t)(n0 + row) * K + k0) * 2 + cb,
                  (char*)Bs + (wid << 12) + (r << 10));
    }
    __syncthreads();
#pragma unroll
    for (int kk = 0; kk < 2; ++kk) {
      bf16x8 af[4], bfr[4];
      int cb = (kk << 6) + ((lane >> 4) << 4);
#pragma unroll
      for (int i = 0; i < 4; ++i) {
        int rA = (wm << 6) + (i << 4) + (lane & 15);
        af[i] = *(const bf16x8*)((const char*)As + rA * 128 + (cb ^ ((rA & 7) << 4)));
        int rB = (wn << 6) + (i << 4) + (lane & 15);
        bfr[i] = *(const bf16x8*)((const char*)Bs + rB * 128 + (cb ^ ((rB & 7) << 4)));
      }
#pragma unroll
      for (int i = 0; i < 4; ++i)
#pragma unroll
        for (int j = 0; j < 4; ++j)
          acc[i][j] = __builtin_amdgcn_mfma_f32_16x16x32_bf16(af[i], bfr[j], acc[i][j], 0, 0, 0);
    }
    __syncthreads();
  }

  const int lr = (lane >> 4) << 2;
  const int lc = lane & 15;
#pragma unroll
  for (int i = 0; i < 4; ++i) {
#pragma unroll
    for (int j = 0; j < 4; ++j) {
      int row = m0 + (wm << 6) + (i << 4) + lr;
      int col = n0 + (wn << 6) + (j << 4) + lc;
      float bv = bias[col];
#pragma unroll
      for (int r = 0; r < 4; ++r) {
        size_t idx = (size_t)(row + r) * N + col;
        float v = acc[i][j][r] + bv;
        if constexpr (EPI == 0) {
          ((bf16*)Cout)[idx] = (bf16)v;
        } else if constexpr (EPI == 1) {
          ((float*)Cout)[idx] = v + resid[idx];
        } else {
          float g = 0.5f * v * (1.0f + erff(v * 0.70710678118654752f));
          ((bf16*)Cout)[idx] = (bf16)g;
        }
      }
    }
  }
}

// ---------------- windowed attention: one (b, h, window) per block ----------------
// qkv: [MTOK][3072] bf16 ([q|k|v], col = h*64+d). out: [MTOK][1024] bf16.
__global__ __launch_bounds__(256) void attn_win(const bf16* __restrict__ qkv,
                                                bf16* __restrict__ out) {
  __shared__ alignas(16) char smem[49152];
  bf16* Qs = (bf16*)smem;              // [128][64] rowbytes=128, swizzled
  bf16* Ks = (bf16*)(smem + 16384);    // same
  bf16* Vt = (bf16*)(smem + 32768);    // [64][128] rowbytes=256, swizzled (V transposed)

  const int tid = threadIdx.x, wid = tid >> 6, lane = tid & 63;
  const int bid = blockIdx.x;
  const int w = bid & 63, h = (bid >> 6) & 15, b = bid >> 10;
  const size_t tok0 = (size_t)b * SEQ + (size_t)w * WIN;
  const char* qbase = (const char*)(qkv + tok0 * 3072 + h * 64);

  // stage Q,K (swizzled source -> linear LDS dest)
#pragma unroll
  for (int r = 0; r < 4; ++r) {
    int o = (wid << 12) + (r << 10) + lane * 16;
    int row = o >> 7;
    int cb = (o & 127) ^ ((row & 7) << 4);
    const char* g = qbase + (size_t)row * 6144 + cb;
    gload_lds16(g,        smem + (wid << 12) + (r << 10));           // Q
    gload_lds16(g + 2048, smem + 16384 + (wid << 12) + (r << 10));   // K
  }
  // stage V transposed: thread -> 2 consecutive k rows x 16 d cols, pack k-pairs (4B writes)
  {
    int k0 = (tid & 63) * 2;
    int dblk = (tid >> 6) * 16;
    const bf16* s0 = qkv + (tok0 + k0) * 3072 + 2048 + h * 64 + dblk;
    bf16x8 r0a = *(const bf16x8*)s0;
    bf16x8 r0b = *(const bf16x8*)(s0 + 8);
    bf16x8 r1a = *(const bf16x8*)(s0 + 3072);
    bf16x8 r1b = *(const bf16x8*)(s0 + 3072 + 8);
#pragma unroll
    for (int e = 0; e < 8; ++e) {
      int d = dblk + e;
      bf16x2 p; p[0] = r0a[e]; p[1] = r1a[e];
      *(bf16x2*)((char*)Vt + d * 256 + ((2 * k0) ^ ((d & 7) << 4))) = p;
      int d2 = dblk + 8 + e;
      bf16x2 p2; p2[0] = r0b[e]; p2[1] = r1b[e];
      *(bf16x2*)((char*)Vt + d2 * 256 + ((2 * k0) ^ ((d2 & 7) << 4))) = p2;
    }
  }
  __syncthreads();

  // S = Q K^T : wave handles 32 q-rows; acc s[i][j] = 16x16 tile (i: q, j: k-col)
  f32x4 s[2][8] = {};
#pragma unroll
  for (int kk = 0; kk < 2; ++kk) {
    bf16x8 aq[2], bk[8];
    int cb = (kk << 6) + ((lane >> 4) << 4);
#pragma unroll
    for (int i = 0; i < 2; ++i) {
      int rA = (wid << 5) + (i << 4) + (lane & 15);
      aq[i] = *(const bf16x8*)((const char*)Qs + rA * 128 + (cb ^ ((rA & 7) << 4)));
    }
#pragma unroll
    for (int j = 0; j < 8; ++j) {
      int rB = (j << 4) + (lane & 15);
      bk[j] = *(const bf16x8*)((const char*)Ks + rB * 128 + (cb ^ ((rB & 7) << 4)));
    }
#pragma unroll
    for (int i = 0; i < 2; ++i)
#pragma unroll
      for (int j = 0; j < 8; ++j)
        s[i][j] = __builtin_amdgcn_mfma_f32_16x16x32_bf16(aq[i], bk[j], s[i][j], 0, 0, 0);
  }
  __syncthreads();   // everyone done reading Q/K before P overwrites that region

  // softmax over rows of 128 (row = (lane>>4)*4+r within tile; 16 lanes share a row)
  float rcp[2][4];
#pragma unroll
  for (int i = 0; i < 2; ++i) {
#pragma unroll
    for (int r = 0; r < 4; ++r) {
      float mx = -1e30f;
#pragma unroll
      for (int j = 0; j < 8; ++j) { s[i][j][r] *= 0.125f; mx = fmaxf(mx, s[i][j][r]); }
#pragma unroll
      for (int off = 8; off; off >>= 1) mx = fmaxf(mx, __shfl_xor(mx, off));
      float sum = 0.f;
#pragma unroll
      for (int j = 0; j < 8; ++j) { float p = __expf(s[i][j][r] - mx); s[i][j][r] = p; sum += p; }
#pragma unroll
      for (int off = 8; off; off >>= 1) sum += __shfl_xor(sum, off);
      rcp[i][r] = 1.f / sum;
    }
  }

  // write P (bf16) into reclaimed Qs/Ks region: per-wave 32x128, rowbytes=256, swizzled
  bf16* Pw = (bf16*)(smem + (wid << 13));
#pragma unroll
  for (int i = 0; i < 2; ++i)
#pragma unroll
    for (int j = 0; j < 8; ++j)
#pragma unroll
      for (int r = 0; r < 4; ++r) {
        int pr = (i << 4) + ((lane >> 4) << 2) + r;
        int pc = (j << 4) + (lane & 15);
        *(bf16*)((char*)Pw + pr * 256 + ((2 * pc) ^ ((pr & 7) << 4))) = (bf16)s[i][j][r];
      }

  // O = P V  (wave-private P, shared Vt; no barrier needed)
  f32x4 oacc[2][4] = {};
#pragma unroll
  for (int kk = 0; kk < 4; ++kk) {
    bf16x8 ap[2], bv[4];
    int cb = (kk << 6) + ((lane >> 4) << 4);
#pragma unroll
    for (int i = 0; i < 2; ++i) {
      int pr = (i << 4) + (lane & 15);
      ap[i] = *(const bf16x8*)((const char*)Pw + pr * 256 + (cb ^ ((pr & 7) << 4)));
    }
#pragma unroll
    for (int n = 0; n < 4; ++n) {
      int vr = (n << 4) + (lane & 15);
      bv[n] = *(const bf16x8*)((const char*)Vt + vr * 256 + (cb ^ ((vr & 7) << 4)));
    }
#pragma unroll
    for (int i = 0; i < 2; ++i)
#pragma unroll
      for (int n = 0; n < 4; ++n)
        oacc[i][n] = __builtin_amdgcn_mfma_f32_16x16x32_bf16(ap[i], bv[n], oacc[i][n], 0, 0, 0);
  }

  // epilogue: O * (1/rowsum) -> out[token][h*64+d]
#pragma unroll
  for (int i = 0; i < 2; ++i)
#pragma unroll
    for (int n = 0; n < 4; ++n)
#pragma unroll
      for (int r = 0; r < 4; ++r) {
        int q = (wid << 5) + (i << 4) + ((lane >> 4) << 2) + r;
        int d = (n << 4) + (lane & 15);
        out[(tok0 + q) * 1024 + h * 64 + d] = (bf16)(oacc[i][n][r] * rcp[i][r]);
      }
}

// ---------------- launch ----------------
extern "C" void kernel_launch(void* const* d_in, const int* in_sizes, int n_in,
                              void* d_out, int out_size, void* d_ws, size_t ws_size,
                              hipStream_t stream) {
  const float* x     = (const float*)d_in[0];
  const float* ln1w  = (const float*)d_in[1];
  const float* ln1b  = (const float*)d_in[2];
  const float* qkvw  = (const float*)d_in[3];
  const float* qkvb  = (const float*)d_in[4];
  const float* projw = (const float*)d_in[5];
  const float* projb = (const float*)d_in[6];
  const float* ln2w  = (const float*)d_in[7];
  const float* ln2b  = (const float*)d_in[8];
  const float* fc1w  = (const float*)d_in[9];
  const float* fc1b  = (const float*)d_in[10];
  const float* fc2w  = (const float*)d_in[11];
  const float* fc2b  = (const float*)d_in[12];
  float* out = (float*)d_out;

  char* ws = (char*)d_ws;
  bf16* lnbuf = (bf16*)ws;                          // 64 MB (ln1 out; reused: attn out, ln2 out)
  bf16* qkv   = (bf16*)(ws + ((size_t)64 << 20));   // 192 MB (reused: MLP hidden h)
  bf16* attnb = lnbuf;
  bf16* hbuf  = qkv;
  bf16* wq    = (bf16*)(ws + ((size_t)256 << 20));  // bf16 weights ~16.5 MB total
  bf16* wp    = wq + 3072 * 1024;
  bf16* w1    = wp + 1024 * 1024;
  bf16* w2    = w1 + 2048 * 1024;
  // d_out doubles as fp32 x1 scratch (x + attn), consumed by ln2 and fc2's residual.

  cvt_w<<<3072, 256, 0, stream>>>(qkvw, wq, 3072 * 1024 / 4);
  cvt_w<<<1024, 256, 0, stream>>>(projw, wp, 1024 * 1024 / 4);
  cvt_w<<<2048, 256, 0, stream>>>(fc1w, w1, 2048 * 1024 / 4);
  cvt_w<<<2048, 256, 0, stream>>>(fc2w, w2, 1024 * 2048 / 4);

  ln_bf16<<<MTOK, 256, 0, stream>>>(x, ln1w, ln1b, lnbuf);
  gemm_bt<3072, 1024, 0><<<dim3(24, 256), 256, 0, stream>>>(lnbuf, wq, qkvb, nullptr, qkv);
  attn_win<<<4096, 256, 0, stream>>>(qkv, attnb);
  gemm_bt<1024, 1024, 1><<<dim3(8, 256), 256, 0, stream>>>(attnb, wp, projb, x, out);
  ln_bf16<<<MTOK, 256, 0, stream>>>(out, ln2w, ln2b, lnbuf);
  gemm_bt<2048, 1024, 2><<<dim3(16, 256), 256, 0, stream>>>(lnbuf, w1, fc1b, nullptr, hbuf);
  gemm_bt<1024, 2048, 1><<<dim3(8, 256), 256, 0, stream>>>(hbuf, w2, fc2b, out, out);
}

// Round 2
// 1018.698 us; speedup vs baseline: 1.1602x; 1.1602x over previous
//
#include <hip/hip_runtime.h>
#include <hip/hip_bf16.h>
#include <math.h>

// ---------------- types / constants ----------------
#define AS1 __attribute__((address_space(1)))
#define AS3 __attribute__((address_space(3)))

typedef __bf16 bf16;
typedef __bf16 bf16x2 __attribute__((ext_vector_type(2)));
typedef __bf16 bf16x4 __attribute__((ext_vector_type(4)));
typedef __bf16 bf16x8 __attribute__((ext_vector_type(8)));
typedef float  f32x4  __attribute__((ext_vector_type(4)));

#define DIM   1024
#define HEADS 16
#define WIN   128
#define NBAT  4
#define SEQ   8192
#define MTOK  (NBAT*SEQ)   // 32768 tokens

__device__ __forceinline__ void gload_lds16(const void* g, void* l) {
  __builtin_amdgcn_global_load_lds((const AS1 void*)g, (AS3 void*)l, 16, 0, 0);
}

// ---------------- fp32 -> bf16 weight convert ----------------
__global__ __launch_bounds__(256) void cvt_w(const float* __restrict__ in,
                                             bf16* __restrict__ out, int n4) {
  int i = blockIdx.x * 256 + threadIdx.x;
  if (i < n4) {
    float4 v = ((const float4*)in)[i];
    bf16x4 o;
    o[0] = (bf16)v.x; o[1] = (bf16)v.y; o[2] = (bf16)v.z; o[3] = (bf16)v.w;
    ((bf16x4*)out)[i] = o;
  }
}

// ---------------- LayerNorm (one row of 1024 per block) -> bf16 ----------------
__global__ __launch_bounds__(256) void ln_bf16(const float* __restrict__ x,
                                               const float* __restrict__ w,
                                               const float* __restrict__ b,
                                               bf16* __restrict__ out) {
  int row = blockIdx.x;
  int t = threadIdx.x;
  float4 v = ((const float4*)(x + (size_t)row * DIM))[t];
  float s  = v.x + v.y + v.z + v.w;
  float ss = v.x*v.x + v.y*v.y + v.z*v.z + v.w*v.w;
#pragma unroll
  for (int off = 32; off; off >>= 1) { s += __shfl_xor(s, off); ss += __shfl_xor(ss, off); }
  __shared__ float sb[8];
  int wid = t >> 6, lane = t & 63;
  if (!lane) { sb[wid] = s; sb[wid + 4] = ss; }
  __syncthreads();
  s  = sb[0] + sb[1] + sb[2] + sb[3];
  ss = sb[4] + sb[5] + sb[6] + sb[7];
  float mu = s * (1.0f / DIM);
  float rs = rsqrtf(ss * (1.0f / DIM) - mu * mu + 1e-5f);
  float4 wv = ((const float4*)w)[t];
  float4 bv = ((const float4*)b)[t];
  bf16x4 o;
  o[0] = (bf16)((v.x - mu) * rs * wv.x + bv.x);
  o[1] = (bf16)((v.y - mu) * rs * wv.y + bv.y);
  o[2] = (bf16)((v.z - mu) * rs * wv.z + bv.z);
  o[3] = (bf16)((v.w - mu) * rs * wv.w + bv.w);
  ((bf16x4*)(out + (size_t)row * DIM))[t] = o;
}

// ---------------- 256x256 8-phase BT-GEMM: C[M,N] = A[M,K]*Bw[N,K]^T + epi ----
// 8 waves (2M x 4N), BK=64, double-buffered 128KB LDS, counted vmcnt (T3+T4),
// T2 XOR swizzle (proven, 0 conflicts), T5 setprio around MFMA clusters.
// EPI 0: +bias -> bf16 ; EPI 1: +bias +resid -> fp32 ; EPI 2: gelu(+bias) -> bf16
#define MFMA16(base_)                                                          \
  _Pragma("unroll") for (int kk = 0; kk < 2; ++kk)                             \
  _Pragma("unroll") for (int i = 0; i < 2; ++i)                                \
  _Pragma("unroll") for (int nj = 0; nj < 4; ++nj)                             \
    acc[(base_) + i][nj] = __builtin_amdgcn_mfma_f32_16x16x32_bf16(            \
        afrag[i][kk], bfrag[nj][kk], acc[(base_) + i][nj], 0, 0, 0);

#define READ_A(i_, mi_) {                                                      \
    int rA_ = wm * 128 + (mi_) * 16 + fr;                                      \
    afrag[i_][0] = *(const bf16x8*)(Ab_ + rA_ * 128 + ((fcb)      ^ fsw));     \
    afrag[i_][1] = *(const bf16x8*)(Ab_ + rA_ * 128 + ((64 + fcb) ^ fsw)); }

template<int N, int K, int EPI>
__global__ __launch_bounds__(512, 2) void gemm256(const bf16* __restrict__ A,
                                                  const bf16* __restrict__ Bw,
                                                  const float* __restrict__ bias,
                                                  const float* __restrict__ resid,
                                                  void* __restrict__ Cout) {
  extern __shared__ char lds[];          // 131072: buf b: A at b*65536, B at +32768
  constexpr int NT = K / 64;
  constexpr int K2 = K * 2;
  const int tid = threadIdx.x;
  const int w = tid >> 6, lane = tid & 63;
  const int wm = w >> 2, wn = w & 3;     // 2x4 wave grid; per-wave out 128x64
  const int m0 = blockIdx.y * 256, n0 = blockIdx.x * 256;

  // staging: per-lane pre-swizzled global source (chunk = 8 rows x 128B)
  const int srow = lane >> 3;
  const int ssw  = ((lane & 7) ^ srow) << 4;
  const char* Asrc = (const char*)A + (size_t)(m0 + srow) * K2 + ssw;
  const char* Bsrc = (const char*)Bw + (size_t)(n0 + srow) * K2 + ssw;

  // fragment-read lane constants
  const int fr  = lane & 15;
  const int fcb = (lane >> 4) << 4;
  const int fsw = (fr & 7) << 4;

  f32x4 acc[8][4] = {};

  // ---- prologue: A(0), B(0), B(1); wait all but B(1) ----
  {
    char* A0 = lds;
    char* B0 = lds + 32768;
    char* B1 = lds + 65536 + 32768;
    gload_lds16(Asrc + (size_t)((w     ) * 8) * K2, A0 + (w     ) * 1024);
    gload_lds16(Asrc + (size_t)((16 + w) * 8) * K2, A0 + (16 + w) * 1024);
    gload_lds16(Asrc + (size_t)((8  + w) * 8) * K2, A0 + (8  + w) * 1024);
    gload_lds16(Asrc + (size_t)((24 + w) * 8) * K2, A0 + (24 + w) * 1024);
    gload_lds16(Bsrc + (size_t)((w     ) * 8) * K2, B0 + (w     ) * 1024);
    gload_lds16(Bsrc + (size_t)((8  + w) * 8) * K2, B0 + (8  + w) * 1024);
    gload_lds16(Bsrc + (size_t)((16 + w) * 8) * K2, B0 + (16 + w) * 1024);
    gload_lds16(Bsrc + (size_t)((24 + w) * 8) * K2, B0 + (24 + w) * 1024);
    const size_t k1 = (NT > 1 ? 1 : 0) * 128;
    gload_lds16(Bsrc + (size_t)((w     ) * 8) * K2 + k1, B1 + (w     ) * 1024);
    gload_lds16(Bsrc + (size_t)((8  + w) * 8) * K2 + k1, B1 + (8  + w) * 1024);
    gload_lds16(Bsrc + (size_t)((16 + w) * 8) * K2 + k1, B1 + (16 + w) * 1024);
    gload_lds16(Bsrc + (size_t)((24 + w) * 8) * K2 + k1, B1 + (24 + w) * 1024);
    asm volatile("s_waitcnt vmcnt(4)" ::: "memory");
    __builtin_amdgcn_s_barrier();
  }

#pragma unroll 1
  for (int t = 0; t < NT; ++t) {
    const char* Ab_ = lds + (t & 1) * 65536;
    const char* Bb_ = Ab_ + 32768;
    char* An = lds + ((t + 1) & 1) * 65536;            // A(t+1) dest
    char* Bn = lds + (t & 1) * 65536 + 32768;          // B(t+2) dest (= current B region, dead after ph0)
    const size_t ka = (size_t)((t + 1 < NT) ? t + 1 : NT - 1) * 128;
    const size_t kb = (size_t)((t + 2 < NT) ? t + 2 : NT - 1) * 128;

    bf16x8 bfrag[4][2], afrag[2][2];

    // ---- phase 0: read all B + A mi0-1; issue A(t+1) q0,q2 ----
#pragma unroll
    for (int nj = 0; nj < 4; ++nj) {
      int rB = wn * 64 + nj * 16 + fr;
      bfrag[nj][0] = *(const bf16x8*)(Bb_ + rB * 128 + ((fcb)      ^ fsw));
      bfrag[nj][1] = *(const bf16x8*)(Bb_ + rB * 128 + ((64 + fcb) ^ fsw));
    }
    READ_A(0, 0) READ_A(1, 1)
    gload_lds16(Asrc + (size_t)((w     ) * 8) * K2 + ka, An + (w     ) * 1024);
    gload_lds16(Asrc + (size_t)((16 + w) * 8) * K2 + ka, An + (16 + w) * 1024);
    __builtin_amdgcn_s_barrier();
    __builtin_amdgcn_s_setprio(1);
    MFMA16(0)
    __builtin_amdgcn_s_setprio(0);
    __builtin_amdgcn_s_barrier();

    // ---- phase 1: A mi2-3; issue A(t+1) q1,q3; end: vmcnt(8) ----
    READ_A(0, 2) READ_A(1, 3)
    gload_lds16(Asrc + (size_t)((8  + w) * 8) * K2 + ka, An + (8  + w) * 1024);
    gload_lds16(Asrc + (size_t)((24 + w) * 8) * K2 + ka, An + (24 + w) * 1024);
    __builtin_amdgcn_s_barrier();
    __builtin_amdgcn_s_setprio(1);
    MFMA16(2)
    __builtin_amdgcn_s_setprio(0);
    asm volatile("s_waitcnt vmcnt(8)" ::: "memory");   // A(t) q1,q3 landed
    __builtin_amdgcn_s_barrier();

    // ---- phase 2: A mi4-5; issue B(t+2) c0,c1 ----
    READ_A(0, 4) READ_A(1, 5)
    gload_lds16(Bsrc + (size_t)((w     ) * 8) * K2 + kb, Bn + (w     ) * 1024);
    gload_lds16(Bsrc + (size_t)((8  + w) * 8) * K2 + kb, Bn + (8  + w) * 1024);
    __builtin_amdgcn_s_barrier();
    __builtin_amdgcn_s_setprio(1);
    MFMA16(4)
    __builtin_amdgcn_s_setprio(0);
    __builtin_amdgcn_s_barrier();

    // ---- phase 3: A mi6-7; issue B(t+2) c2,c3; boundary: vmcnt(6) ----
    READ_A(0, 6) READ_A(1, 7)
    gload_lds16(Bsrc + (size_t)((16 + w) * 8) * K2 + kb, Bn + (16 + w) * 1024);
    gload_lds16(Bsrc + (size_t)((24 + w) * 8) * K2 + kb, Bn + (24 + w) * 1024);
    __builtin_amdgcn_s_barrier();
    __builtin_amdgcn_s_setprio(1);
    MFMA16(6)
    __builtin_amdgcn_s_setprio(0);
    asm volatile("s_waitcnt vmcnt(6)" ::: "memory");   // B(t+1) + A(t+1) q0,q2 landed
    __builtin_amdgcn_s_barrier();
  }

  // ---- epilogue ----
  const int lr4 = (lane >> 4) << 2;
#pragma unroll
  for (int mi = 0; mi < 8; ++mi) {
#pragma unroll
    for (int nj = 0; nj < 4; ++nj) {
      int row = m0 + wm * 128 + mi * 16 + lr4;
      int col = n0 + wn * 64 + nj * 16 + fr;
      float bv = bias[col];
#pragma unroll
      for (int r = 0; r < 4; ++r) {
        size_t idx = (size_t)(row + r) * N + col;
        float v = acc[mi][nj][r] + bv;
        if constexpr (EPI == 0) {
          ((bf16*)Cout)[idx] = (bf16)v;
        } else if constexpr (EPI == 1) {
          ((float*)Cout)[idx] = v + resid[idx];
        } else {
          float g = 0.5f * v * (1.0f + erff(v * 0.70710678118654752f));
          ((bf16*)Cout)[idx] = (bf16)g;
        }
      }
    }
  }
}

// ---------------- windowed attention: one (b, h, window) per block ----------------
__global__ __launch_bounds__(256) void attn_win(const bf16* __restrict__ qkv,
                                                bf16* __restrict__ out) {
  __shared__ alignas(16) char smem[49152];
  bf16* Vt = (bf16*)(smem + 32768);

  const int tid = threadIdx.x, wid = tid >> 6, lane = tid & 63;
  const int bid = blockIdx.x;
  const int w = bid & 63, h = (bid >> 6) & 15, b = bid >> 10;
  const size_t tok0 = (size_t)b * SEQ + (size_t)w * WIN;
  const char* qbase = (const char*)(qkv + tok0 * 3072 + h * 64);

#pragma unroll
  for (int r = 0; r < 4; ++r) {
    int o = (wid << 12) + (r << 10) + lane * 16;
    int row = o >> 7;
    int cb = (o & 127) ^ ((row & 7) << 4);
    const char* g = qbase + (size_t)row * 6144 + cb;
    gload_lds16(g,        smem + (wid << 12) + (r << 10));           // Q
    gload_lds16(g + 2048, smem + 16384 + (wid << 12) + (r << 10));   // K
  }
  {
    int k0 = (tid & 63) * 2;
    int dblk = (tid >> 6) * 16;
    const bf16* s0 = qkv + (tok0 + k0) * 3072 + 2048 + h * 64 + dblk;
    bf16x8 r0a = *(const bf16x8*)s0;
    bf16x8 r0b = *(const bf16x8*)(s0 + 8);
    bf16x8 r1a = *(const bf16x8*)(s0 + 3072);
    bf16x8 r1b = *(const bf16x8*)(s0 + 3072 + 8);
#pragma unroll
    for (int e = 0; e < 8; ++e) {
      int d = dblk + e;
      bf16x2 p; p[0] = r0a[e]; p[1] = r1a[e];
      *(bf16x2*)((char*)Vt + d * 256 + ((2 * k0) ^ ((d & 7) << 4))) = p;
      int d2 = dblk + 8 + e;
      bf16x2 p2; p2[0] = r0b[e]; p2[1] = r1b[e];
      *(bf16x2*)((char*)Vt + d2 * 256 + ((2 * k0) ^ ((d2 & 7) << 4))) = p2;
    }
  }
  __syncthreads();

  f32x4 s[2][8] = {};
#pragma unroll
  for (int kk = 0; kk < 2; ++kk) {
    bf16x8 aq[2], bk[8];
    int cb = (kk << 6) + ((lane >> 4) << 4);
#pragma unroll
    for (int i = 0; i < 2; ++i) {
      int rA = (wid << 5) + (i << 4) + (lane & 15);
      aq[i] = *(const bf16x8*)(smem + rA * 128 + (cb ^ ((rA & 7) << 4)));
    }
#pragma unroll
    for (int j = 0; j < 8; ++j) {
      int rB = (j << 4) + (lane & 15);
      bk[j] = *(const bf16x8*)(smem + 16384 + rB * 128 + (cb ^ ((rB & 7) << 4)));
    }
#pragma unroll
    for (int i = 0; i < 2; ++i)
#pragma unroll
      for (int j = 0; j < 8; ++j)
        s[i][j] = __builtin_amdgcn_mfma_f32_16x16x32_bf16(aq[i], bk[j], s[i][j], 0, 0, 0);
  }
  __syncthreads();

  float rcp[2][4];
#pragma unroll
  for (int i = 0; i < 2; ++i) {
#pragma unroll
    for (int r = 0; r < 4; ++r) {
      float mx = -1e30f;
#pragma unroll
      for (int j = 0; j < 8; ++j) { s[i][j][r] *= 0.125f; mx = fmaxf(mx, s[i][j][r]); }
#pragma unroll
      for (int off = 8; off; off >>= 1) mx = fmaxf(mx, __shfl_xor(mx, off));
      float sum = 0.f;
#pragma unroll
      for (int j = 0; j < 8; ++j) { float p = __expf(s[i][j][r] - mx); s[i][j][r] = p; sum += p; }
#pragma unroll
      for (int off = 8; off; off >>= 1) sum += __shfl_xor(sum, off);
      rcp[i][r] = 1.f / sum;
    }
  }

  bf16* Pw = (bf16*)(smem + (wid << 13));
#pragma unroll
  for (int i = 0; i < 2; ++i)
#pragma unroll
    for (int j = 0; j < 8; ++j)
#pragma unroll
      for (int r = 0; r < 4; ++r) {
        int pr = (i << 4) + ((lane >> 4) << 2) + r;
        int pc = (j << 4) + (lane & 15);
        *(bf16*)((char*)Pw + pr * 256 + ((2 * pc) ^ ((pr & 7) << 4))) = (bf16)s[i][j][r];
      }

  f32x4 oacc[2][4] = {};
#pragma unroll
  for (int kk = 0; kk < 4; ++kk) {
    bf16x8 ap[2], bv[4];
    int cb = (kk << 6) + ((lane >> 4) << 4);
#pragma unroll
    for (int i = 0; i < 2; ++i) {
      int pr = (i << 4) + (lane & 15);
      ap[i] = *(const bf16x8*)((const char*)Pw + pr * 256 + (cb ^ ((pr & 7) << 4)));
    }
#pragma unroll
    for (int n = 0; n < 4; ++n) {
      int vr = (n << 4) + (lane & 15);
      bv[n] = *(const bf16x8*)((const char*)Vt + vr * 256 + (cb ^ ((vr & 7) << 4)));
    }
#pragma unroll
    for (int i = 0; i < 2; ++i)
#pragma unroll
      for (int n = 0; n < 4; ++n)
        oacc[i][n] = __builtin_amdgcn_mfma_f32_16x16x32_bf16(ap[i], bv[n], oacc[i][n], 0, 0, 0);
  }

#pragma unroll
  for (int i = 0; i < 2; ++i)
#pragma unroll
    for (int n = 0; n < 4; ++n)
#pragma unroll
      for (int r = 0; r < 4; ++r) {
        int q = (wid << 5) + (i << 4) + ((lane >> 4) << 2) + r;
        int d = (n << 4) + (lane & 15);
        out[(tok0 + q) * 1024 + h * 64 + d] = (bf16)(oacc[i][n][r] * rcp[i][r]);
      }
}

// ---------------- launch ----------------
extern "C" void kernel_launch(void* const* d_in, const int* in_sizes, int n_in,
                              void* d_out, int out_size, void* d_ws, size_t ws_size,
                              hipStream_t stream) {
  const float* x     = (const float*)d_in[0];
  const float* ln1w  = (const float*)d_in[1];
  const float* ln1b  = (const float*)d_in[2];
  const float* qkvw  = (const float*)d_in[3];
  const float* qkvb  = (const float*)d_in[4];
  const float* projw = (const float*)d_in[5];
  const float* projb = (const float*)d_in[6];
  const float* ln2w  = (const float*)d_in[7];
  const float* ln2b  = (const float*)d_in[8];
  const float* fc1w  = (const float*)d_in[9];
  const float* fc1b  = (const float*)d_in[10];
  const float* fc2w  = (const float*)d_in[11];
  const float* fc2b  = (const float*)d_in[12];
  float* out = (float*)d_out;

  char* ws = (char*)d_ws;
  bf16* lnbuf = (bf16*)ws;                          // 64 MB
  bf16* qkv   = (bf16*)(ws + ((size_t)64 << 20));   // 192 MB (reused as MLP hidden)
  bf16* attnb = lnbuf;
  bf16* hbuf  = qkv;
  bf16* wq    = (bf16*)(ws + ((size_t)256 << 20));
  bf16* wp    = wq + 3072 * 1024;
  bf16* w1    = wp + 1024 * 1024;
  bf16* w2    = w1 + 2048 * 1024;

  // allow 128 KB dynamic LDS (idempotent host-side calls; not stream ops)
  hipFuncSetAttribute((const void*)gemm256<3072, 1024, 0>, hipFuncAttributeMaxDynamicSharedMemorySize, 131072);
  hipFuncSetAttribute((const void*)gemm256<1024, 1024, 1>, hipFuncAttributeMaxDynamicSharedMemorySize, 131072);
  hipFuncSetAttribute((const void*)gemm256<2048, 1024, 2>, hipFuncAttributeMaxDynamicSharedMemorySize, 131072);
  hipFuncSetAttribute((const void*)gemm256<1024, 2048, 1>, hipFuncAttributeMaxDynamicSharedMemorySize, 131072);

  cvt_w<<<3072, 256, 0, stream>>>(qkvw, wq, 3072 * 1024 / 4);
  cvt_w<<<1024, 256, 0, stream>>>(projw, wp, 1024 * 1024 / 4);
  cvt_w<<<2048, 256, 0, stream>>>(fc1w, w1, 2048 * 1024 / 4);
  cvt_w<<<2048, 256, 0, stream>>>(fc2w, w2, 1024 * 2048 / 4);

  ln_bf16<<<MTOK, 256, 0, stream>>>(x, ln1w, ln1b, lnbuf);
  gemm256<3072, 1024, 0><<<dim3(12, 128), 512, 131072, stream>>>(lnbuf, wq, qkvb, nullptr, qkv);
  attn_win<<<4096, 256, 0, stream>>>(qkv, attnb);
  gemm256<1024, 1024, 1><<<dim3(4, 128), 512, 131072, stream>>>(attnb, wp, projb, x, out);
  ln_bf16<<<MTOK, 256, 0, stream>>>(out, ln2w, ln2b, lnbuf);
  gemm256<2048, 1024, 2><<<dim3(8, 128), 512, 131072, stream>>>(lnbuf, w1, fc1b, nullptr, hbuf);
  gemm256<1024, 2048, 1><<<dim3(4, 128), 512, 131072, stream>>>(hbuf, w2, fc2b, out, out);
}

// Round 3
// 1011.899 us; speedup vs baseline: 1.1680x; 1.0067x over previous
//
#include <hip/hip_runtime.h>
#include <hip/hip_bf16.h>
#include <math.h>

// ---------------- types / constants ----------------
#define AS1 __attribute__((address_space(1)))
#define AS3 __attribute__((address_space(3)))

typedef __bf16 bf16;
typedef __bf16 bf16x2 __attribute__((ext_vector_type(2)));
typedef __bf16 bf16x4 __attribute__((ext_vector_type(4)));
typedef __bf16 bf16x8 __attribute__((ext_vector_type(8)));
typedef float  f32x4  __attribute__((ext_vector_type(4)));

#define DIM   1024
#define HEADS 16
#define WIN   128
#define NBAT  4
#define SEQ   8192
#define MTOK  (NBAT*SEQ)   // 32768 tokens

__device__ __forceinline__ void gload_lds16(const void* g, void* l) {
  __builtin_amdgcn_global_load_lds((const AS1 void*)g, (AS3 void*)l, 16, 0, 0);
}

// ---------------- fp32 -> bf16 weight convert ----------------
__global__ __launch_bounds__(256) void cvt_w(const float* __restrict__ in,
                                             bf16* __restrict__ out, int n4) {
  int i = blockIdx.x * 256 + threadIdx.x;
  if (i < n4) {
    float4 v = ((const float4*)in)[i];
    bf16x4 o;
    o[0] = (bf16)v.x; o[1] = (bf16)v.y; o[2] = (bf16)v.z; o[3] = (bf16)v.w;
    ((bf16x4*)out)[i] = o;
  }
}

// ---------------- LayerNorm (one row of 1024 per block) -> bf16 ----------------
__global__ __launch_bounds__(256) void ln_bf16(const float* __restrict__ x,
                                               const float* __restrict__ w,
                                               const float* __restrict__ b,
                                               bf16* __restrict__ out) {
  int row = blockIdx.x;
  int t = threadIdx.x;
  float4 v = ((const float4*)(x + (size_t)row * DIM))[t];
  float s  = v.x + v.y + v.z + v.w;
  float ss = v.x*v.x + v.y*v.y + v.z*v.z + v.w*v.w;
#pragma unroll
  for (int off = 32; off; off >>= 1) { s += __shfl_xor(s, off); ss += __shfl_xor(ss, off); }
  __shared__ float sb[8];
  int wid = t >> 6, lane = t & 63;
  if (!lane) { sb[wid] = s; sb[wid + 4] = ss; }
  __syncthreads();
  s  = sb[0] + sb[1] + sb[2] + sb[3];
  ss = sb[4] + sb[5] + sb[6] + sb[7];
  float mu = s * (1.0f / DIM);
  float rs = rsqrtf(ss * (1.0f / DIM) - mu * mu + 1e-5f);
  float4 wv = ((const float4*)w)[t];
  float4 bv = ((const float4*)b)[t];
  bf16x4 o;
  o[0] = (bf16)((v.x - mu) * rs * wv.x + bv.x);
  o[1] = (bf16)((v.y - mu) * rs * wv.y + bv.y);
  o[2] = (bf16)((v.z - mu) * rs * wv.z + bv.z);
  o[3] = (bf16)((v.w - mu) * rs * wv.w + bv.w);
  ((bf16x4*)(out + (size_t)row * DIM))[t] = o;
}

// ---------------- 256x256 8-phase BT-GEMM: C[M,N] = A[M,K]*Bw[N,K]^T + epi ----
// 8 waves (2M x 4N), BK=64, double-buffered 128KB LDS, counted vmcnt (T3+T4),
// T2 XOR swizzle, T5 setprio, grouped super-tile block mapping (R3 lever):
// 1-D grid, m = g*8 + rem%8, n = rem/8 -> 8xNBX-block window touches 4MB of A
// + whole B weight (fits aggregate L2; A fetched from HBM once).
// EPI 0: +bias -> bf16 ; EPI 1: +bias +resid -> fp32 ; EPI 2: gelu(+bias) -> bf16
#define MFMA16(base_)                                                          \
  _Pragma("unroll") for (int kk = 0; kk < 2; ++kk)                             \
  _Pragma("unroll") for (int i = 0; i < 2; ++i)                                \
  _Pragma("unroll") for (int nj = 0; nj < 4; ++nj)                             \
    acc[(base_) + i][nj] = __builtin_amdgcn_mfma_f32_16x16x32_bf16(            \
        afrag[i][kk], bfrag[nj][kk], acc[(base_) + i][nj], 0, 0, 0);

#define READ_A(i_, mi_) {                                                      \
    int rA_ = wm * 128 + (mi_) * 16 + fr;                                      \
    afrag[i_][0] = *(const bf16x8*)(Ab_ + rA_ * 128 + ((fcb)      ^ fsw));     \
    afrag[i_][1] = *(const bf16x8*)(Ab_ + rA_ * 128 + ((64 + fcb) ^ fsw)); }

template<int N, int K, int EPI>
__global__ __launch_bounds__(512, 2) void gemm256(const bf16* __restrict__ A,
                                                  const bf16* __restrict__ Bw,
                                                  const float* __restrict__ bias,
                                                  const float* __restrict__ resid,
                                                  void* __restrict__ Cout) {
  extern __shared__ char lds[];          // 131072: buf b: A at b*65536, B at +32768
  constexpr int NT = K / 64;
  constexpr int K2 = K * 2;
  constexpr int NBX = N / 256;
  constexpr int PG = 8 * NBX;
  const int tid = threadIdx.x;
  const int w = tid >> 6, lane = tid & 63;
  const int wm = w >> 2, wn = w & 3;     // 2x4 wave grid; per-wave out 128x64
  // grouped super-tile mapping (bijective: bid in [0, NBX*128))
  const int bid = blockIdx.x;
  const int g = bid / PG, rem = bid - g * PG;
  const int m0 = (g * 8 + (rem & 7)) * 256;
  const int n0 = (rem >> 3) * 256;

  // staging: per-lane pre-swizzled global source (chunk = 8 rows x 128B)
  const int srow = lane >> 3;
  const int ssw  = ((lane & 7) ^ srow) << 4;
  const char* Asrc = (const char*)A + (size_t)(m0 + srow) * K2 + ssw;
  const char* Bsrc = (const char*)Bw + (size_t)(n0 + srow) * K2 + ssw;

  // fragment-read lane constants
  const int fr  = lane & 15;
  const int fcb = (lane >> 4) << 4;
  const int fsw = (fr & 7) << 4;

  f32x4 acc[8][4] = {};

  // ---- prologue: A(0), B(0), B(1); wait all but B(1) ----
  {
    char* A0 = lds;
    char* B0 = lds + 32768;
    char* B1 = lds + 65536 + 32768;
    gload_lds16(Asrc + (size_t)((w     ) * 8) * K2, A0 + (w     ) * 1024);
    gload_lds16(Asrc + (size_t)((16 + w) * 8) * K2, A0 + (16 + w) * 1024);
    gload_lds16(Asrc + (size_t)((8  + w) * 8) * K2, A0 + (8  + w) * 1024);
    gload_lds16(Asrc + (size_t)((24 + w) * 8) * K2, A0 + (24 + w) * 1024);
    gload_lds16(Bsrc + (size_t)((w     ) * 8) * K2, B0 + (w     ) * 1024);
    gload_lds16(Bsrc + (size_t)((8  + w) * 8) * K2, B0 + (8  + w) * 1024);
    gload_lds16(Bsrc + (size_t)((16 + w) * 8) * K2, B0 + (16 + w) * 1024);
    gload_lds16(Bsrc + (size_t)((24 + w) * 8) * K2, B0 + (24 + w) * 1024);
    const size_t k1 = (NT > 1 ? 1 : 0) * 128;
    gload_lds16(Bsrc + (size_t)((w     ) * 8) * K2 + k1, B1 + (w     ) * 1024);
    gload_lds16(Bsrc + (size_t)((8  + w) * 8) * K2 + k1, B1 + (8  + w) * 1024);
    gload_lds16(Bsrc + (size_t)((16 + w) * 8) * K2 + k1, B1 + (16 + w) * 1024);
    gload_lds16(Bsrc + (size_t)((24 + w) * 8) * K2 + k1, B1 + (24 + w) * 1024);
    asm volatile("s_waitcnt vmcnt(4)" ::: "memory");
    __builtin_amdgcn_s_barrier();
  }

#pragma unroll 1
  for (int t = 0; t < NT; ++t) {
    const char* Ab_ = lds + (t & 1) * 65536;
    const char* Bb_ = Ab_ + 32768;
    char* An = lds + ((t + 1) & 1) * 65536;            // A(t+1) dest
    char* Bn = lds + (t & 1) * 65536 + 32768;          // B(t+2) dest (= current B region, dead after ph0)
    const size_t ka = (size_t)((t + 1 < NT) ? t + 1 : NT - 1) * 128;
    const size_t kb = (size_t)((t + 2 < NT) ? t + 2 : NT - 1) * 128;

    bf16x8 bfrag[4][2], afrag[2][2];

    // ---- phase 0: read all B + A mi0-1; issue A(t+1) q0,q2 ----
#pragma unroll
    for (int nj = 0; nj < 4; ++nj) {
      int rB = wn * 64 + nj * 16 + fr;
      bfrag[nj][0] = *(const bf16x8*)(Bb_ + rB * 128 + ((fcb)      ^ fsw));
      bfrag[nj][1] = *(const bf16x8*)(Bb_ + rB * 128 + ((64 + fcb) ^ fsw));
    }
    READ_A(0, 0) READ_A(1, 1)
    gload_lds16(Asrc + (size_t)((w     ) * 8) * K2 + ka, An + (w     ) * 1024);
    gload_lds16(Asrc + (size_t)((16 + w) * 8) * K2 + ka, An + (16 + w) * 1024);
    __builtin_amdgcn_s_barrier();
    __builtin_amdgcn_s_setprio(1);
    MFMA16(0)
    __builtin_amdgcn_s_setprio(0);
    __builtin_amdgcn_s_barrier();

    // ---- phase 1: A mi2-3; issue A(t+1) q1,q3; end: vmcnt(8) ----
    READ_A(0, 2) READ_A(1, 3)
    gload_lds16(Asrc + (size_t)((8  + w) * 8) * K2 + ka, An + (8  + w) * 1024);
    gload_lds16(Asrc + (size_t)((24 + w) * 8) * K2 + ka, An + (24 + w) * 1024);
    __builtin_amdgcn_s_barrier();
    __builtin_amdgcn_s_setprio(1);
    MFMA16(2)
    __builtin_amdgcn_s_setprio(0);
    asm volatile("s_waitcnt vmcnt(8)" ::: "memory");   // A(t) q1,q3 landed
    __builtin_amdgcn_s_barrier();

    // ---- phase 2: A mi4-5; issue B(t+2) c0,c1 ----
    READ_A(0, 4) READ_A(1, 5)
    gload_lds16(Bsrc + (size_t)((w     ) * 8) * K2 + kb, Bn + (w     ) * 1024);
    gload_lds16(Bsrc + (size_t)((8  + w) * 8) * K2 + kb, Bn + (8  + w) * 1024);
    __builtin_amdgcn_s_barrier();
    __builtin_amdgcn_s_setprio(1);
    MFMA16(4)
    __builtin_amdgcn_s_setprio(0);
    __builtin_amdgcn_s_barrier();

    // ---- phase 3: A mi6-7; issue B(t+2) c2,c3; boundary: vmcnt(6) ----
    READ_A(0, 6) READ_A(1, 7)
    gload_lds16(Bsrc + (size_t)((16 + w) * 8) * K2 + kb, Bn + (16 + w) * 1024);
    gload_lds16(Bsrc + (size_t)((24 + w) * 8) * K2 + kb, Bn + (24 + w) * 1024);
    __builtin_amdgcn_s_barrier();
    __builtin_amdgcn_s_setprio(1);
    MFMA16(6)
    __builtin_amdgcn_s_setprio(0);
    asm volatile("s_waitcnt vmcnt(6)" ::: "memory");   // B(t+1) + A(t+1) q0,q2 landed
    __builtin_amdgcn_s_barrier();
  }

  // ---- epilogue ----
  const int lr4 = (lane >> 4) << 2;
#pragma unroll
  for (int mi = 0; mi < 8; ++mi) {
#pragma unroll
    for (int nj = 0; nj < 4; ++nj) {
      int row = m0 + wm * 128 + mi * 16 + lr4;
      int col = n0 + wn * 64 + nj * 16 + fr;
      float bv = bias[col];
#pragma unroll
      for (int r = 0; r < 4; ++r) {
        size_t idx = (size_t)(row + r) * N + col;
        float v = acc[mi][nj][r] + bv;
        if constexpr (EPI == 0) {
          ((bf16*)Cout)[idx] = (bf16)v;
        } else if constexpr (EPI == 1) {
          ((float*)Cout)[idx] = v + resid[idx];
        } else {
          float g = 0.5f * v * (1.0f + erff(v * 0.70710678118654752f));
          ((bf16*)Cout)[idx] = (bf16)g;
        }
      }
    }
  }
}

// ---------------- windowed attention: one (b, h, window) per block ----------------
__global__ __launch_bounds__(256) void attn_win(const bf16* __restrict__ qkv,
                                                bf16* __restrict__ out) {
  __shared__ alignas(16) char smem[49152];
  bf16* Vt = (bf16*)(smem + 32768);

  const int tid = threadIdx.x, wid = tid >> 6, lane = tid & 63;
  const int bid = blockIdx.x;
  const int w = bid & 63, h = (bid >> 6) & 15, b = bid >> 10;
  const size_t tok0 = (size_t)b * SEQ + (size_t)w * WIN;
  const char* qbase = (const char*)(qkv + tok0 * 3072 + h * 64);

#pragma unroll
  for (int r = 0; r < 4; ++r) {
    int o = (wid << 12) + (r << 10) + lane * 16;
    int row = o >> 7;
    int cb = (o & 127) ^ ((row & 7) << 4);
    const char* g = qbase + (size_t)row * 6144 + cb;
    gload_lds16(g,        smem + (wid << 12) + (r << 10));           // Q
    gload_lds16(g + 2048, smem + 16384 + (wid << 12) + (r << 10));   // K
  }
  {
    int k0 = (tid & 63) * 2;
    int dblk = (tid >> 6) * 16;
    const bf16* s0 = qkv + (tok0 + k0) * 3072 + 2048 + h * 64 + dblk;
    bf16x8 r0a = *(const bf16x8*)s0;
    bf16x8 r0b = *(const bf16x8*)(s0 + 8);
    bf16x8 r1a = *(const bf16x8*)(s0 + 3072);
    bf16x8 r1b = *(const bf16x8*)(s0 + 3072 + 8);
#pragma unroll
    for (int e = 0; e < 8; ++e) {
      int d = dblk + e;
      bf16x2 p; p[0] = r0a[e]; p[1] = r1a[e];
      *(bf16x2*)((char*)Vt + d * 256 + ((2 * k0) ^ ((d & 7) << 4))) = p;
      int d2 = dblk + 8 + e;
      bf16x2 p2; p2[0] = r0b[e]; p2[1] = r1b[e];
      *(bf16x2*)((char*)Vt + d2 * 256 + ((2 * k0) ^ ((d2 & 7) << 4))) = p2;
    }
  }
  __syncthreads();

  f32x4 s[2][8] = {};
#pragma unroll
  for (int kk = 0; kk < 2; ++kk) {
    bf16x8 aq[2], bk[8];
    int cb = (kk << 6) + ((lane >> 4) << 4);
#pragma unroll
    for (int i = 0; i < 2; ++i) {
      int rA = (wid << 5) + (i << 4) + (lane & 15);
      aq[i] = *(const bf16x8*)(smem + rA * 128 + (cb ^ ((rA & 7) << 4)));
    }
#pragma unroll
    for (int j = 0; j < 8; ++j) {
      int rB = (j << 4) + (lane & 15);
      bk[j] = *(const bf16x8*)(smem + 16384 + rB * 128 + (cb ^ ((rB & 7) << 4)));
    }
#pragma unroll
    for (int i = 0; i < 2; ++i)
#pragma unroll
      for (int j = 0; j < 8; ++j)
        s[i][j] = __builtin_amdgcn_mfma_f32_16x16x32_bf16(aq[i], bk[j], s[i][j], 0, 0, 0);
  }
  __syncthreads();

  float rcp[2][4];
#pragma unroll
  for (int i = 0; i < 2; ++i) {
#pragma unroll
    for (int r = 0; r < 4; ++r) {
      float mx = -1e30f;
#pragma unroll
      for (int j = 0; j < 8; ++j) { s[i][j][r] *= 0.125f; mx = fmaxf(mx, s[i][j][r]); }
#pragma unroll
      for (int off = 8; off; off >>= 1) mx = fmaxf(mx, __shfl_xor(mx, off));
      float sum = 0.f;
#pragma unroll
      for (int j = 0; j < 8; ++j) { float p = __expf(s[i][j][r] - mx); s[i][j][r] = p; sum += p; }
#pragma unroll
      for (int off = 8; off; off >>= 1) sum += __shfl_xor(sum, off);
      rcp[i][r] = 1.f / sum;
    }
  }

  bf16* Pw = (bf16*)(smem + (wid << 13));
#pragma unroll
  for (int i = 0; i < 2; ++i)
#pragma unroll
    for (int j = 0; j < 8; ++j)
#pragma unroll
      for (int r = 0; r < 4; ++r) {
        int pr = (i << 4) + ((lane >> 4) << 2) + r;
        int pc = (j << 4) + (lane & 15);
        *(bf16*)((char*)Pw + pr * 256 + ((2 * pc) ^ ((pr & 7) << 4))) = (bf16)s[i][j][r];
      }

  f32x4 oacc[2][4] = {};
#pragma unroll
  for (int kk = 0; kk < 4; ++kk) {
    bf16x8 ap[2], bv[4];
    int cb = (kk << 6) + ((lane >> 4) << 4);
#pragma unroll
    for (int i = 0; i < 2; ++i) {
      int pr = (i << 4) + (lane & 15);
      ap[i] = *(const bf16x8*)((const char*)Pw + pr * 256 + (cb ^ ((pr & 7) << 4)));
    }
#pragma unroll
    for (int n = 0; n < 4; ++n) {
      int vr = (n << 4) + (lane & 15);
      bv[n] = *(const bf16x8*)((const char*)Vt + vr * 256 + (cb ^ ((vr & 7) << 4)));
    }
#pragma unroll
    for (int i = 0; i < 2; ++i)
#pragma unroll
      for (int n = 0; n < 4; ++n)
        oacc[i][n] = __builtin_amdgcn_mfma_f32_16x16x32_bf16(ap[i], bv[n], oacc[i][n], 0, 0, 0);
  }

#pragma unroll
  for (int i = 0; i < 2; ++i)
#pragma unroll
    for (int n = 0; n < 4; ++n)
#pragma unroll
      for (int r = 0; r < 4; ++r) {
        int q = (wid << 5) + (i << 4) + ((lane >> 4) << 2) + r;
        int d = (n << 4) + (lane & 15);
        out[(tok0 + q) * 1024 + h * 64 + d] = (bf16)(oacc[i][n][r] * rcp[i][r]);
      }
}

// ---------------- launch ----------------
extern "C" void kernel_launch(void* const* d_in, const int* in_sizes, int n_in,
                              void* d_out, int out_size, void* d_ws, size_t ws_size,
                              hipStream_t stream) {
  const float* x     = (const float*)d_in[0];
  const float* ln1w  = (const float*)d_in[1];
  const float* ln1b  = (const float*)d_in[2];
  const float* qkvw  = (const float*)d_in[3];
  const float* qkvb  = (const float*)d_in[4];
  const float* projw = (const float*)d_in[5];
  const float* projb = (const float*)d_in[6];
  const float* ln2w  = (const float*)d_in[7];
  const float* ln2b  = (const float*)d_in[8];
  const float* fc1w  = (const float*)d_in[9];
  const float* fc1b  = (const float*)d_in[10];
  const float* fc2w  = (const float*)d_in[11];
  const float* fc2b  = (const float*)d_in[12];
  float* out = (float*)d_out;

  char* ws = (char*)d_ws;
  bf16* lnbuf = (bf16*)ws;                          // 64 MB
  bf16* qkv   = (bf16*)(ws + ((size_t)64 << 20));   // 192 MB (reused as MLP hidden)
  bf16* attnb = lnbuf;
  bf16* hbuf  = qkv;
  bf16* wq    = (bf16*)(ws + ((size_t)256 << 20));
  bf16* wp    = wq + 3072 * 1024;
  bf16* w1    = wp + 1024 * 1024;
  bf16* w2    = w1 + 2048 * 1024;

  hipFuncSetAttribute((const void*)gemm256<3072, 1024, 0>, hipFuncAttributeMaxDynamicSharedMemorySize, 131072);
  hipFuncSetAttribute((const void*)gemm256<1024, 1024, 1>, hipFuncAttributeMaxDynamicSharedMemorySize, 131072);
  hipFuncSetAttribute((const void*)gemm256<2048, 1024, 2>, hipFuncAttributeMaxDynamicSharedMemorySize, 131072);
  hipFuncSetAttribute((const void*)gemm256<1024, 2048, 1>, hipFuncAttributeMaxDynamicSharedMemorySize, 131072);

  cvt_w<<<3072, 256, 0, stream>>>(qkvw, wq, 3072 * 1024 / 4);
  cvt_w<<<1024, 256, 0, stream>>>(projw, wp, 1024 * 1024 / 4);
  cvt_w<<<2048, 256, 0, stream>>>(fc1w, w1, 2048 * 1024 / 4);
  cvt_w<<<2048, 256, 0, stream>>>(fc2w, w2, 1024 * 2048 / 4);

  ln_bf16<<<MTOK, 256, 0, stream>>>(x, ln1w, ln1b, lnbuf);
  gemm256<3072, 1024, 0><<<12 * 128, 512, 131072, stream>>>(lnbuf, wq, qkvb, nullptr, qkv);
  attn_win<<<4096, 256, 0, stream>>>(qkv, attnb);
  gemm256<1024, 1024, 1><<<4 * 128, 512, 131072, stream>>>(attnb, wp, projb, x, out);
  ln_bf16<<<MTOK, 256, 0, stream>>>(out, ln2w, ln2b, lnbuf);
  gemm256<2048, 1024, 2><<<8 * 128, 512, 131072, stream>>>(lnbuf, w1, fc1b, nullptr, hbuf);
  gemm256<1024, 2048, 1><<<4 * 128, 512, 131072, stream>>>(hbuf, w2, fc2b, out, out);
}

// Round 4
// 1007.491 us; speedup vs baseline: 1.1731x; 1.0044x over previous
//
#include <hip/hip_runtime.h>
#include <hip/hip_bf16.h>
#include <math.h>

// ---------------- types / constants ----------------
#define AS1 __attribute__((address_space(1)))
#define AS3 __attribute__((address_space(3)))

typedef __bf16 bf16;
typedef __bf16 bf16x2 __attribute__((ext_vector_type(2)));
typedef __bf16 bf16x4 __attribute__((ext_vector_type(4)));
typedef __bf16 bf16x8 __attribute__((ext_vector_type(8)));
typedef float  f32x4  __attribute__((ext_vector_type(4)));

#define DIM   1024
#define HEADS 16
#define WIN   128
#define NBAT  4
#define SEQ   8192
#define MTOK  (NBAT*SEQ)   // 32768 tokens

__device__ __forceinline__ void gload_lds16(const void* g, void* l) {
  __builtin_amdgcn_global_load_lds((const AS1 void*)g, (AS3 void*)l, 16, 0, 0);
}

// ---------------- fp32 -> bf16 weight convert ----------------
__global__ __launch_bounds__(256) void cvt_w(const float* __restrict__ in,
                                             bf16* __restrict__ out, int n4) {
  int i = blockIdx.x * 256 + threadIdx.x;
  if (i < n4) {
    float4 v = ((const float4*)in)[i];
    bf16x4 o;
    o[0] = (bf16)v.x; o[1] = (bf16)v.y; o[2] = (bf16)v.z; o[3] = (bf16)v.w;
    ((bf16x4*)out)[i] = o;
  }
}

// ---------------- LayerNorm (one row of 1024 per block) -> bf16 ----------------
__global__ __launch_bounds__(256) void ln_bf16(const float* __restrict__ x,
                                               const float* __restrict__ w,
                                               const float* __restrict__ b,
                                               bf16* __restrict__ out) {
  int row = blockIdx.x;
  int t = threadIdx.x;
  float4 v = ((const float4*)(x + (size_t)row * DIM))[t];
  float s  = v.x + v.y + v.z + v.w;
  float ss = v.x*v.x + v.y*v.y + v.z*v.z + v.w*v.w;
#pragma unroll
  for (int off = 32; off; off >>= 1) { s += __shfl_xor(s, off); ss += __shfl_xor(ss, off); }
  __shared__ float sb[8];
  int wid = t >> 6, lane = t & 63;
  if (!lane) { sb[wid] = s; sb[wid + 4] = ss; }
  __syncthreads();
  s  = sb[0] + sb[1] + sb[2] + sb[3];
  ss = sb[4] + sb[5] + sb[6] + sb[7];
  float mu = s * (1.0f / DIM);
  float rs = rsqrtf(ss * (1.0f / DIM) - mu * mu + 1e-5f);
  float4 wv = ((const float4*)w)[t];
  float4 bv = ((const float4*)b)[t];
  bf16x4 o;
  o[0] = (bf16)((v.x - mu) * rs * wv.x + bv.x);
  o[1] = (bf16)((v.y - mu) * rs * wv.y + bv.y);
  o[2] = (bf16)((v.z - mu) * rs * wv.z + bv.z);
  o[3] = (bf16)((v.w - mu) * rs * wv.w + bv.w);
  ((bf16x4*)(out + (size_t)row * DIM))[t] = o;
}

// ---------------- 256x256 8-phase BT-GEMM: C[M,N] = A[M,K]*Bw[N,K]^T + epi ----
// 8 waves (2M x 4N), BK=64, double-buffered 128KB LDS, counted vmcnt (T3+T4),
// T2 XOR swizzle, T5 setprio, grouped super-tile mapping.
// R4: balanced LDS-read phases 8/8/4/4 — phase = (mi-quad x all-nj x one kk);
// B-frags for both kk live in registers across the tile (WAR-safe: B(t+2)
// staging issues after ph2-entry barrier, which postdates all ph1 B-reads).
// EPI 0: +bias -> bf16 ; EPI 1: +bias +resid -> fp32 ; EPI 2: gelu(+bias) -> bf16
template<int N, int K, int EPI>
__global__ __launch_bounds__(512, 2) void gemm256(const bf16* __restrict__ A,
                                                  const bf16* __restrict__ Bw,
                                                  const float* __restrict__ bias,
                                                  const float* __restrict__ resid,
                                                  void* __restrict__ Cout) {
  extern __shared__ char lds[];          // 131072: buf b: A at b*65536, B at +32768
  constexpr int NT = K / 64;
  constexpr int K2 = K * 2;
  constexpr int NBX = N / 256;
  constexpr int PG = 8 * NBX;
  const int tid = threadIdx.x;
  const int w = tid >> 6, lane = tid & 63;
  const int wm = w >> 2, wn = w & 3;     // 2x4 wave grid; per-wave out 128x64
  // grouped super-tile mapping (bijective: bid in [0, NBX*128))
  const int bid = blockIdx.x;
  const int g = bid / PG, rem = bid - g * PG;
  const int m0 = (g * 8 + (rem & 7)) * 256;
  const int n0 = (rem >> 3) * 256;

  // staging: per-lane pre-swizzled global source (chunk = 8 rows x 128B)
  const int srow = lane >> 3;
  const int ssw  = ((lane & 7) ^ srow) << 4;
  const char* Asrc = (const char*)A + (size_t)(m0 + srow) * K2 + ssw;
  const char* Bsrc = (const char*)Bw + (size_t)(n0 + srow) * K2 + ssw;

  // fragment-read lane constants
  const int fr  = lane & 15;
  const int fcb = (lane >> 4) << 4;
  const int fsw = (fr & 7) << 4;

  f32x4 acc[8][4] = {};

  // ---- prologue: A(0), B(0), B(1); wait all but B(1) ----
  {
    char* A0 = lds;
    char* B0 = lds + 32768;
    char* B1 = lds + 65536 + 32768;
    gload_lds16(Asrc + (size_t)((w     ) * 8) * K2, A0 + (w     ) * 1024);
    gload_lds16(Asrc + (size_t)((16 + w) * 8) * K2, A0 + (16 + w) * 1024);
    gload_lds16(Asrc + (size_t)((8  + w) * 8) * K2, A0 + (8  + w) * 1024);
    gload_lds16(Asrc + (size_t)((24 + w) * 8) * K2, A0 + (24 + w) * 1024);
    gload_lds16(Bsrc + (size_t)((w     ) * 8) * K2, B0 + (w     ) * 1024);
    gload_lds16(Bsrc + (size_t)((8  + w) * 8) * K2, B0 + (8  + w) * 1024);
    gload_lds16(Bsrc + (size_t)((16 + w) * 8) * K2, B0 + (16 + w) * 1024);
    gload_lds16(Bsrc + (size_t)((24 + w) * 8) * K2, B0 + (24 + w) * 1024);
    const size_t k1 = (NT > 1 ? 1 : 0) * 128;
    gload_lds16(Bsrc + (size_t)((w     ) * 8) * K2 + k1, B1 + (w     ) * 1024);
    gload_lds16(Bsrc + (size_t)((8  + w) * 8) * K2 + k1, B1 + (8  + w) * 1024);
    gload_lds16(Bsrc + (size_t)((16 + w) * 8) * K2 + k1, B1 + (16 + w) * 1024);
    gload_lds16(Bsrc + (size_t)((24 + w) * 8) * K2 + k1, B1 + (24 + w) * 1024);
    asm volatile("s_waitcnt vmcnt(4)" ::: "memory");
    __builtin_amdgcn_s_barrier();
  }

#pragma unroll 1
  for (int t = 0; t < NT; ++t) {
    const char* Ab_ = lds + (t & 1) * 65536;
    const char* Bb_ = Ab_ + 32768;
    char* An = lds + ((t + 1) & 1) * 65536;            // A(t+1) dest
    char* Bn = lds + (t & 1) * 65536 + 32768;          // B(t+2) dest (current B region, dead after ph1)
    const size_t ka = (size_t)((t + 1 < NT) ? t + 1 : NT - 1) * 128;
    const size_t kb = (size_t)((t + 2 < NT) ? t + 2 : NT - 1) * 128;

    bf16x8 bfrag[4][2];
    bf16x8 afrag[4];

    // ---- phase 0: read B[kk0] + A[mi0-3][kk0] (8 reads); issue A(t+1) q0,q2 ----
#pragma unroll
    for (int nj = 0; nj < 4; ++nj) {
      int rB = wn * 64 + nj * 16 + fr;
      bfrag[nj][0] = *(const bf16x8*)(Bb_ + rB * 128 + (fcb ^ fsw));
    }
#pragma unroll
    for (int mi = 0; mi < 4; ++mi) {
      int rA = wm * 128 + mi * 16 + fr;
      afrag[mi] = *(const bf16x8*)(Ab_ + rA * 128 + (fcb ^ fsw));
    }
    gload_lds16(Asrc + (size_t)((w     ) * 8) * K2 + ka, An + (w     ) * 1024);
    gload_lds16(Asrc + (size_t)((16 + w) * 8) * K2 + ka, An + (16 + w) * 1024);
    __builtin_amdgcn_s_barrier();
    __builtin_amdgcn_s_setprio(1);
#pragma unroll
    for (int mi = 0; mi < 4; ++mi)
#pragma unroll
      for (int nj = 0; nj < 4; ++nj)
        acc[mi][nj] = __builtin_amdgcn_mfma_f32_16x16x32_bf16(afrag[mi], bfrag[nj][0], acc[mi][nj], 0, 0, 0);
    __builtin_amdgcn_s_setprio(0);
    __builtin_amdgcn_s_barrier();

    // ---- phase 1: read B[kk1] + A[mi0-3][kk1] (8 reads); issue A(t+1) q1,q3; vmcnt(8) ----
#pragma unroll
    for (int nj = 0; nj < 4; ++nj) {
      int rB = wn * 64 + nj * 16 + fr;
      bfrag[nj][1] = *(const bf16x8*)(Bb_ + rB * 128 + ((64 + fcb) ^ fsw));
    }
#pragma unroll
    for (int mi = 0; mi < 4; ++mi) {
      int rA = wm * 128 + mi * 16 + fr;
      afrag[mi] = *(const bf16x8*)(Ab_ + rA * 128 + ((64 + fcb) ^ fsw));
    }
    gload_lds16(Asrc + (size_t)((8  + w) * 8) * K2 + ka, An + (8  + w) * 1024);
    gload_lds16(Asrc + (size_t)((24 + w) * 8) * K2 + ka, An + (24 + w) * 1024);
    __builtin_amdgcn_s_barrier();
    __builtin_amdgcn_s_setprio(1);
#pragma unroll
    for (int mi = 0; mi < 4; ++mi)
#pragma unroll
      for (int nj = 0; nj < 4; ++nj)
        acc[mi][nj] = __builtin_amdgcn_mfma_f32_16x16x32_bf16(afrag[mi], bfrag[nj][1], acc[mi][nj], 0, 0, 0);
    __builtin_amdgcn_s_setprio(0);
    asm volatile("s_waitcnt vmcnt(8)" ::: "memory");   // A(t) q1,q3 landed
    __builtin_amdgcn_s_barrier();

    // ---- phase 2: read A[mi4-7][kk0] (4 reads); issue B(t+2) c0,c1 ----
#pragma unroll
    for (int mi = 0; mi < 4; ++mi) {
      int rA = wm * 128 + (4 + mi) * 16 + fr;
      afrag[mi] = *(const bf16x8*)(Ab_ + rA * 128 + (fcb ^ fsw));
    }
    gload_lds16(Bsrc + (size_t)((w     ) * 8) * K2 + kb, Bn + (w     ) * 1024);
    gload_lds16(Bsrc + (size_t)((8  + w) * 8) * K2 + kb, Bn + (8  + w) * 1024);
    __builtin_amdgcn_s_barrier();
    __builtin_amdgcn_s_setprio(1);
#pragma unroll
    for (int mi = 0; mi < 4; ++mi)
#pragma unroll
      for (int nj = 0; nj < 4; ++nj)
        acc[4 + mi][nj] = __builtin_amdgcn_mfma_f32_16x16x32_bf16(afrag[mi], bfrag[nj][0], acc[4 + mi][nj], 0, 0, 0);
    __builtin_amdgcn_s_setprio(0);
    __builtin_amdgcn_s_barrier();

    // ---- phase 3: read A[mi4-7][kk1] (4 reads); issue B(t+2) c2,c3; vmcnt(6) ----
#pragma unroll
    for (int mi = 0; mi < 4; ++mi) {
      int rA = wm * 128 + (4 + mi) * 16 + fr;
      afrag[mi] = *(const bf16x8*)(Ab_ + rA * 128 + ((64 + fcb) ^ fsw));
    }
    gload_lds16(Bsrc + (size_t)((16 + w) * 8) * K2 + kb, Bn + (16 + w) * 1024);
    gload_lds16(Bsrc + (size_t)((24 + w) * 8) * K2 + kb, Bn + (24 + w) * 1024);
    __builtin_amdgcn_s_barrier();
    __builtin_amdgcn_s_setprio(1);
#pragma unroll
    for (int mi = 0; mi < 4; ++mi)
#pragma unroll
      for (int nj = 0; nj < 4; ++nj)
        acc[4 + mi][nj] = __builtin_amdgcn_mfma_f32_16x16x32_bf16(afrag[mi], bfrag[nj][1], acc[4 + mi][nj], 0, 0, 0);
    __builtin_amdgcn_s_setprio(0);
    asm volatile("s_waitcnt vmcnt(6)" ::: "memory");   // B(t+1) + A(t+1) q0,q2 landed
    __builtin_amdgcn_s_barrier();
  }

  // ---- epilogue ----
  const int lr4 = (lane >> 4) << 2;
#pragma unroll
  for (int mi = 0; mi < 8; ++mi) {
#pragma unroll
    for (int nj = 0; nj < 4; ++nj) {
      int row = m0 + wm * 128 + mi * 16 + lr4;
      int col = n0 + wn * 64 + nj * 16 + fr;
      float bv = bias[col];
#pragma unroll
      for (int r = 0; r < 4; ++r) {
        size_t idx = (size_t)(row + r) * N + col;
        float v = acc[mi][nj][r] + bv;
        if constexpr (EPI == 0) {
          ((bf16*)Cout)[idx] = (bf16)v;
        } else if constexpr (EPI == 1) {
          ((float*)Cout)[idx] = v + resid[idx];
        } else {
          float g = 0.5f * v * (1.0f + erff(v * 0.70710678118654752f));
          ((bf16*)Cout)[idx] = (bf16)g;
        }
      }
    }
  }
}

// ---------------- windowed attention: one (b, h, window) per block ----------------
__global__ __launch_bounds__(256) void attn_win(const bf16* __restrict__ qkv,
                                                bf16* __restrict__ out) {
  __shared__ alignas(16) char smem[49152];
  bf16* Vt = (bf16*)(smem + 32768);

  const int tid = threadIdx.x, wid = tid >> 6, lane = tid & 63;
  const int bid = blockIdx.x;
  const int w = bid & 63, h = (bid >> 6) & 15, b = bid >> 10;
  const size_t tok0 = (size_t)b * SEQ + (size_t)w * WIN;
  const char* qbase = (const char*)(qkv + tok0 * 3072 + h * 64);

#pragma unroll
  for (int r = 0; r < 4; ++r) {
    int o = (wid << 12) + (r << 10) + lane * 16;
    int row = o >> 7;
    int cb = (o & 127) ^ ((row & 7) << 4);
    const char* g = qbase + (size_t)row * 6144 + cb;
    gload_lds16(g,        smem + (wid << 12) + (r << 10));           // Q
    gload_lds16(g + 2048, smem + 16384 + (wid << 12) + (r << 10));   // K
  }
  {
    int k0 = (tid & 63) * 2;
    int dblk = (tid >> 6) * 16;
    const bf16* s0 = qkv + (tok0 + k0) * 3072 + 2048 + h * 64 + dblk;
    bf16x8 r0a = *(const bf16x8*)s0;
    bf16x8 r0b = *(const bf16x8*)(s0 + 8);
    bf16x8 r1a = *(const bf16x8*)(s0 + 3072);
    bf16x8 r1b = *(const bf16x8*)(s0 + 3072 + 8);
#pragma unroll
    for (int e = 0; e < 8; ++e) {
      int d = dblk + e;
      bf16x2 p; p[0] = r0a[e]; p[1] = r1a[e];
      *(bf16x2*)((char*)Vt + d * 256 + ((2 * k0) ^ ((d & 7) << 4))) = p;
      int d2 = dblk + 8 + e;
      bf16x2 p2; p2[0] = r0b[e]; p2[1] = r1b[e];
      *(bf16x2*)((char*)Vt + d2 * 256 + ((2 * k0) ^ ((d2 & 7) << 4))) = p2;
    }
  }
  __syncthreads();

  f32x4 s[2][8] = {};
#pragma unroll
  for (int kk = 0; kk < 2; ++kk) {
    bf16x8 aq[2], bk[8];
    int cb = (kk << 6) + ((lane >> 4) << 4);
#pragma unroll
    for (int i = 0; i < 2; ++i) {
      int rA = (wid << 5) + (i << 4) + (lane & 15);
      aq[i] = *(const bf16x8*)(smem + rA * 128 + (cb ^ ((rA & 7) << 4)));
    }
#pragma unroll
    for (int j = 0; j < 8; ++j) {
      int rB = (j << 4) + (lane & 15);
      bk[j] = *(const bf16x8*)(smem + 16384 + rB * 128 + (cb ^ ((rB & 7) << 4)));
    }
#pragma unroll
    for (int i = 0; i < 2; ++i)
#pragma unroll
      for (int j = 0; j < 8; ++j)
        s[i][j] = __builtin_amdgcn_mfma_f32_16x16x32_bf16(aq[i], bk[j], s[i][j], 0, 0, 0);
  }
  __syncthreads();

  float rcp[2][4];
#pragma unroll
  for (int i = 0; i < 2; ++i) {
#pragma unroll
    for (int r = 0; r < 4; ++r) {
      float mx = -1e30f;
#pragma unroll
      for (int j = 0; j < 8; ++j) { s[i][j][r] *= 0.125f; mx = fmaxf(mx, s[i][j][r]); }
#pragma unroll
      for (int off = 8; off; off >>= 1) mx = fmaxf(mx, __shfl_xor(mx, off));
      float sum = 0.f;
#pragma unroll
      for (int j = 0; j < 8; ++j) { float p = __expf(s[i][j][r] - mx); s[i][j][r] = p; sum += p; }
#pragma unroll
      for (int off = 8; off; off >>= 1) sum += __shfl_xor(sum, off);
      rcp[i][r] = 1.f / sum;
    }
  }

  bf16* Pw = (bf16*)(smem + (wid << 13));
#pragma unroll
  for (int i = 0; i < 2; ++i)
#pragma unroll
    for (int j = 0; j < 8; ++j)
#pragma unroll
      for (int r = 0; r < 4; ++r) {
        int pr = (i << 4) + ((lane >> 4) << 2) + r;
        int pc = (j << 4) + (lane & 15);
        *(bf16*)((char*)Pw + pr * 256 + ((2 * pc) ^ ((pr & 7) << 4))) = (bf16)s[i][j][r];
      }

  f32x4 oacc[2][4] = {};
#pragma unroll
  for (int kk = 0; kk < 4; ++kk) {
    bf16x8 ap[2], bv[4];
    int cb = (kk << 6) + ((lane >> 4) << 4);
#pragma unroll
    for (int i = 0; i < 2; ++i) {
      int pr = (i << 4) + (lane & 15);
      ap[i] = *(const bf16x8*)((const char*)Pw + pr * 256 + (cb ^ ((pr & 7) << 4)));
    }
#pragma unroll
    for (int n = 0; n < 4; ++n) {
      int vr = (n << 4) + (lane & 15);
      bv[n] = *(const bf16x8*)((const char*)Vt + vr * 256 + (cb ^ ((vr & 7) << 4)));
    }
#pragma unroll
    for (int i = 0; i < 2; ++i)
#pragma unroll
      for (int n = 0; n < 4; ++n)
        oacc[i][n] = __builtin_amdgcn_mfma_f32_16x16x32_bf16(ap[i], bv[n], oacc[i][n], 0, 0, 0);
  }

#pragma unroll
  for (int i = 0; i < 2; ++i)
#pragma unroll
    for (int n = 0; n < 4; ++n)
#pragma unroll
      for (int r = 0; r < 4; ++r) {
        int q = (wid << 5) + (i << 4) + ((lane >> 4) << 2) + r;
        int d = (n << 4) + (lane & 15);
        out[(tok0 + q) * 1024 + h * 64 + d] = (bf16)(oacc[i][n][r] * rcp[i][r]);
      }
}

// ---------------- launch ----------------
extern "C" void kernel_launch(void* const* d_in, const int* in_sizes, int n_in,
                              void* d_out, int out_size, void* d_ws, size_t ws_size,
                              hipStream_t stream) {
  const float* x     = (const float*)d_in[0];
  const float* ln1w  = (const float*)d_in[1];
  const float* ln1b  = (const float*)d_in[2];
  const float* qkvw  = (const float*)d_in[3];
  const float* qkvb  = (const float*)d_in[4];
  const float* projw = (const float*)d_in[5];
  const float* projb = (const float*)d_in[6];
  const float* ln2w  = (const float*)d_in[7];
  const float* ln2b  = (const float*)d_in[8];
  const float* fc1w  = (const float*)d_in[9];
  const float* fc1b  = (const float*)d_in[10];
  const float* fc2w  = (const float*)d_in[11];
  const float* fc2b  = (const float*)d_in[12];
  float* out = (float*)d_out;

  char* ws = (char*)d_ws;
  bf16* lnbuf = (bf16*)ws;                          // 64 MB
  bf16* qkv   = (bf16*)(ws + ((size_t)64 << 20));   // 192 MB (reused as MLP hidden)
  bf16* attnb = lnbuf;
  bf16* hbuf  = qkv;
  bf16* wq    = (bf16*)(ws + ((size_t)256 << 20));
  bf16* wp    = wq + 3072 * 1024;
  bf16* w1    = wp + 1024 * 1024;
  bf16* w2    = w1 + 2048 * 1024;

  hipFuncSetAttribute((const void*)gemm256<3072, 1024, 0>, hipFuncAttributeMaxDynamicSharedMemorySize, 131072);
  hipFuncSetAttribute((const void*)gemm256<1024, 1024, 1>, hipFuncAttributeMaxDynamicSharedMemorySize, 131072);
  hipFuncSetAttribute((const void*)gemm256<2048, 1024, 2>, hipFuncAttributeMaxDynamicSharedMemorySize, 131072);
  hipFuncSetAttribute((const void*)gemm256<1024, 2048, 1>, hipFuncAttributeMaxDynamicSharedMemorySize, 131072);

  cvt_w<<<3072, 256, 0, stream>>>(qkvw, wq, 3072 * 1024 / 4);
  cvt_w<<<1024, 256, 0, stream>>>(projw, wp, 1024 * 1024 / 4);
  cvt_w<<<2048, 256, 0, stream>>>(fc1w, w1, 2048 * 1024 / 4);
  cvt_w<<<2048, 256, 0, stream>>>(fc2w, w2, 1024 * 2048 / 4);

  ln_bf16<<<MTOK, 256, 0, stream>>>(x, ln1w, ln1b, lnbuf);
  gemm256<3072, 1024, 0><<<12 * 128, 512, 131072, stream>>>(lnbuf, wq, qkvb, nullptr, qkv);
  attn_win<<<4096, 256, 0, stream>>>(qkv, attnb);
  gemm256<1024, 1024, 1><<<4 * 128, 512, 131072, stream>>>(attnb, wp, projb, x, out);
  ln_bf16<<<MTOK, 256, 0, stream>>>(out, ln2w, ln2b, lnbuf);
  gemm256<2048, 1024, 2><<<8 * 128, 512, 131072, stream>>>(lnbuf, w1, fc1b, nullptr, hbuf);
  gemm256<1024, 2048, 1><<<4 * 128, 512, 131072, stream>>>(hbuf, w2, fc2b, out, out);
}